// Round 1
// baseline (556.939 us; speedup 1.0000x reference)
//
#include <hip/hip_runtime.h>
#include <stdint.h>

#define N_ROWS 4096
#define F_DIM  2048
#define B_DIM  2048
#define K_DIM  4096   // F (h part) + B (behavior part)

typedef __attribute__((ext_vector_type(8))) __bf16 bf16x8;
typedef __attribute__((ext_vector_type(4))) float  f32x4;
typedef unsigned short u16;

__device__ __forceinline__ u16 f2bf(float x) {
  unsigned int u = __float_as_uint(x);
  u += 0x7fffu + ((u >> 16) & 1u);   // RNE
  return (u16)(u >> 16);
}

__device__ __forceinline__ void async_copy16(const void* g, void* l) {
  __builtin_amdgcn_global_load_lds(
      (const __attribute__((address_space(1))) void*)g,
      (__attribute__((address_space(3))) void*)l, 16, 0, 0);
}

__device__ __forceinline__ float sigmoid_f(float x) {
  return 1.0f / (1.0f + __expf(-x));
}
__device__ __forceinline__ float tanh_f(float x) {
  float e2 = __expf(2.0f * x);
  return 1.0f - 2.0f / (e2 + 1.0f);
}

// ---------------- pack_x: Xc[n][k] = bf16( k<F ? h0[n][k] : behavior[n][k-F] )
__global__ __launch_bounds__(256) void pack_x_kernel(
    const float* __restrict__ h0, const float* __restrict__ behavior,
    u16* __restrict__ Xc)
{
  int tid = blockIdx.x * 256 + threadIdx.x;  // one thread = 8 consecutive k
  int row = tid >> 9;                        // K_DIM/8 = 512 octets per row
  int k0  = (tid & 511) * 8;
  const float* src = (k0 < F_DIM) ? (h0 + (size_t)row * F_DIM + k0)
                                  : (behavior + (size_t)row * B_DIM + (k0 - F_DIM));
  const float4* s4 = (const float4*)src;
  float4 a = s4[0], b = s4[1];
  uint4 o;
  o.x = (unsigned)f2bf(a.x) | ((unsigned)f2bf(a.y) << 16);
  o.y = (unsigned)f2bf(a.z) | ((unsigned)f2bf(a.w) << 16);
  o.z = (unsigned)f2bf(b.x) | ((unsigned)f2bf(b.y) << 16);
  o.w = (unsigned)f2bf(b.z) | ((unsigned)f2bf(b.w) << 16);
  *(uint4*)(Xc + (size_t)tid * 8) = o;
}

// ---------------- pack_w: WT[g][f][k] = bf16( k<F ? W?_h[k][f] : W?_x[k-F][f] )
__global__ __launch_bounds__(256) void pack_w_kernel(
    const float* __restrict__ wi_h, const float* __restrict__ wi_x,
    const float* __restrict__ wf_h, const float* __restrict__ wf_x,
    const float* __restrict__ wg_h, const float* __restrict__ wg_x,
    const float* __restrict__ wo_h, const float* __restrict__ wo_x,
    u16* __restrict__ WT)
{
  __shared__ float tile[32][33];  // +1 pad breaks bank conflicts on transpose
  int g = blockIdx.z;
  const float* Wh = (g == 0) ? wi_h : (g == 1) ? wf_h : (g == 2) ? wg_h : wo_h;
  const float* Wx = (g == 0) ? wi_x : (g == 1) ? wf_x : (g == 2) ? wg_x : wo_x;
  int fb = blockIdx.x * 32;   // feature (output-col) tile
  int kb = blockIdx.y * 32;   // k tile
  int tx = threadIdx.x & 31;
  int ty = threadIdx.x >> 5;  // 0..7
#pragma unroll
  for (int r = 0; r < 4; ++r) {
    int k = kb + ty + r * 8;
    int f = fb + tx;
    float v = (k < F_DIM) ? Wh[(size_t)k * F_DIM + f]
                          : Wx[(size_t)(k - F_DIM) * F_DIM + f];
    tile[ty + r * 8][tx] = v;  // tile[k_local][f_local]
  }
  __syncthreads();
#pragma unroll
  for (int r = 0; r < 4; ++r) {
    int fl = ty + r * 8;
    int kl = tx;
    WT[((size_t)g * F_DIM + fb + fl) * K_DIM + kb + kl] = f2bf(tile[kl][fl]);
  }
}

// ---------------- fused 4-gate GEMM + LSTM epilogue
// Block: 256 thr (4 waves). Output tile: 128 rows x 32 cols, all 4 gates.
// Wave w -> rows [32w, 32w+32). Per wave/gate: 2x2 frags of 16x16 (mfma 16x16x32).
// LDS: As[128][64] bf16, Bs[4][32][64] bf16 (k-major, XOR-octet swizzled).
// Swizzle: physical 8-elem octet slot s = logical octet o ^ (row & 7)
// -> global_load_lds keeps its mandatory contiguous layout, ds_read_b128 is bank-balanced.
__global__ __launch_bounds__(256) void lstm_gemm_kernel(
    const u16* __restrict__ Xc, const u16* __restrict__ WT,
    const float* __restrict__ c0,
    const float* __restrict__ bi, const float* __restrict__ bff,
    const float* __restrict__ bg, const float* __restrict__ bo,
    float* __restrict__ out)
{
  __shared__ u16 As[128 * 64];      // 16 KB
  __shared__ u16 Bs[4 * 32 * 64];   // 16 KB

  const int tid  = threadIdx.x;
  const int lane = tid & 63;
  const int wv   = tid >> 6;
  const int bn   = blockIdx.x;  // cols bn*32
  const int bm   = blockIdx.y;  // rows bm*128

  // ---- staging descriptors: 8 x 16B chunks per thread per K-tile
  const u16* agp[4];
  const u16* bgp[4];
#pragma unroll
  for (int j = 0; j < 4; ++j) {  // A: chunk c = j*256+tid -> row c/8, slot c%8
    int c = j * 256 + tid;
    int r = c >> 3, s = c & 7, o = s ^ (r & 7);
    agp[j] = Xc + (size_t)(bm * 128 + r) * K_DIM + o * 8;
  }
#pragma unroll
  for (int j = 0; j < 4; ++j) {  // B: gate j, row tid/8, slot tid%8
    int r = tid >> 3, s = tid & 7, o = s ^ (r & 7);
    bgp[j] = WT + ((size_t)j * F_DIM + bn * 32 + r) * K_DIM + o * 8;
  }
  const unsigned ubase = (unsigned)(tid & ~63) * 16u;  // wave-uniform LDS byte offset

  f32x4 acc[4][2][2];
  const f32x4 zero = {0.f, 0.f, 0.f, 0.f};
#pragma unroll
  for (int g = 0; g < 4; ++g)
#pragma unroll
    for (int rh = 0; rh < 2; ++rh)
#pragma unroll
      for (int cf = 0; cf < 2; ++cf) acc[g][rh][cf] = zero;

  const int q = lane >> 4, ln15 = lane & 15;

  for (int kt = 0; kt < 64; ++kt) {
#pragma unroll
    for (int j = 0; j < 4; ++j)
      async_copy16(agp[j], (char*)As + j * 4096 + ubase);
#pragma unroll
    for (int j = 0; j < 4; ++j)
      async_copy16(bgp[j], (char*)Bs + j * 4096 + ubase);
#pragma unroll
    for (int j = 0; j < 4; ++j) { agp[j] += 64; bgp[j] += 64; }
    __syncthreads();  // compiler drains vmcnt here -> staging complete

#pragma unroll
    for (int c = 0; c < 2; ++c) {  // two k-chunks of 32 within the 64-k tile
      bf16x8 af[2];
#pragma unroll
      for (int rh = 0; rh < 2; ++rh) {
        int m = wv * 32 + rh * 16 + ln15;
        int o = c * 4 + q;
        int s = o ^ (m & 7);
        af[rh] = *(const bf16x8*)(As + m * 64 + s * 8);
      }
      bf16x8 bfr[4][2];
#pragma unroll
      for (int g = 0; g < 4; ++g)
#pragma unroll
        for (int cf = 0; cf < 2; ++cf) {
          int n = cf * 16 + ln15;
          int o = c * 4 + q;
          int s = o ^ (n & 7);
          bfr[g][cf] = *(const bf16x8*)(Bs + g * 2048 + n * 64 + s * 8);
        }
#pragma unroll
      for (int g = 0; g < 4; ++g)
#pragma unroll
        for (int rh = 0; rh < 2; ++rh)
#pragma unroll
          for (int cf = 0; cf < 2; ++cf)
            acc[g][rh][cf] = __builtin_amdgcn_mfma_f32_16x16x32_bf16(
                af[rh], bfr[g][cf], acc[g][rh][cf], 0, 0, 0);
    }
    __syncthreads();  // all waves done reading before next overwrite
  }

  // ---- epilogue: C/D layout col = lane&15, row = quad*4 + reg
#pragma unroll
  for (int cf = 0; cf < 2; ++cf) {
    int col = bn * 32 + cf * 16 + ln15;
    float b0 = bi[col], b1 = bff[col], b2 = bg[col], b3 = bo[col];
#pragma unroll
    for (int rh = 0; rh < 2; ++rh) {
      int row0 = bm * 128 + wv * 32 + rh * 16 + q * 4;
#pragma unroll
      for (int r = 0; r < 4; ++r) {
        size_t idx = (size_t)(row0 + r) * F_DIM + col;
        float pi = acc[0][rh][cf][r] + b0;
        float pf = acc[1][rh][cf][r] + b1;
        float pg = acc[2][rh][cf][r] + b2;
        float po = acc[3][rh][cf][r] + b3;
        float iv = sigmoid_f(pi);
        float fv = sigmoid_f(pf);
        float gv = tanh_f(pg);
        float ov = sigmoid_f(po);
        float cv = fv * c0[idx] + iv * gv;
        out[idx] = ov * tanh_f(cv);
      }
    }
  }
}

extern "C" void kernel_launch(void* const* d_in, const int* in_sizes, int n_in,
                              void* d_out, int out_size, void* d_ws, size_t ws_size,
                              hipStream_t stream) {
  const float* behavior = (const float*)d_in[0];
  const float* h0       = (const float*)d_in[1];
  const float* c0       = (const float*)d_in[2];
  const float* Wi_h     = (const float*)d_in[3];
  const float* Wi_x     = (const float*)d_in[4];
  const float* bi       = (const float*)d_in[5];
  const float* Wf_h     = (const float*)d_in[6];
  const float* Wf_x     = (const float*)d_in[7];
  const float* bf       = (const float*)d_in[8];
  const float* Wg_h     = (const float*)d_in[9];
  const float* Wg_x     = (const float*)d_in[10];
  const float* bg       = (const float*)d_in[11];
  const float* Wo_h     = (const float*)d_in[12];
  const float* Wo_x     = (const float*)d_in[13];
  const float* bo       = (const float*)d_in[14];
  float* out = (float*)d_out;

  // workspace: Xc (32 MB bf16) + WT (64 MB bf16) = ~96 MiB
  u16* Xc = (u16*)d_ws;
  u16* WT = Xc + (size_t)N_ROWS * K_DIM;

  pack_x_kernel<<<dim3(N_ROWS * (K_DIM / 8) / 256), 256, 0, stream>>>(h0, behavior, Xc);
  pack_w_kernel<<<dim3(F_DIM / 32, K_DIM / 32, 4), 256, 0, stream>>>(
      Wi_h, Wi_x, Wf_h, Wf_x, Wg_h, Wg_x, Wo_h, Wo_x, WT);
  lstm_gemm_kernel<<<dim3(F_DIM / 32, N_ROWS / 128), 256, 0, stream>>>(
      Xc, WT, c0, bi, bf, bg, bo, out);
}